// Round 1
// baseline (3762.165 us; speedup 1.0000x reference)
//
#include <hip/hip_runtime.h>
#include <hip/hip_bf16.h>

#define TILE 128
#define BK 64

typedef __attribute__((ext_vector_type(8))) short bf16x8;
typedef __attribute__((ext_vector_type(4))) float f32x4;

static __device__ __forceinline__ short f2bf(float f) {
    __hip_bfloat16 h = __float2bfloat16(f);
    return *reinterpret_cast<short*>(&h);
}

// Stage a 128 x 64 fp32 tile from global, converting to bf16 in LDS.
// 256 threads: thread t handles row t>>1, 32 cols starting at (t&1)*32.
static __device__ __forceinline__ void stage_tile(
    const float* __restrict__ src, long long ld, int row0, int k0,
    short (*__restrict__ dst)[BK], int tid)
{
    const int r = tid >> 1;
    const int h = (tid & 1) * 32;
    const float* p = src + (long long)(row0 + r) * ld + k0 + h;
    #pragma unroll
    for (int j = 0; j < 4; ++j) {
        f32x4 x = *reinterpret_cast<const f32x4*>(p + j * 8);
        f32x4 y = *reinterpret_cast<const f32x4*>(p + j * 8 + 4);
        bf16x8 v;
        v[0] = f2bf(x[0]); v[1] = f2bf(x[1]); v[2] = f2bf(x[2]); v[3] = f2bf(x[3]);
        v[4] = f2bf(y[0]); v[5] = f2bf(y[1]); v[6] = f2bf(y[2]); v[7] = f2bf(y[3]);
        *reinterpret_cast<bf16x8*>(&dst[r][h + j * 8]) = v;
    }
}

// Phase 1: fused GEMM tile + per-row online-softmax partials.
// grid = (BT/128, V/128), block = 256 (4 waves, 2x2 wave grid of 64x64).
__global__ __launch_bounds__(256, 2) void ce_gemm_partial(
    const float* __restrict__ inp, const float* __restrict__ wgt,
    const int* __restrict__ target,
    float* __restrict__ pm, float* __restrict__ ps, float* __restrict__ tgt,
    int H, int Vt)
{
    __shared__ __align__(16) short As[TILE][BK];
    __shared__ __align__(16) short Bs[TILE][BK];
    __shared__ float lmax[2][TILE];
    __shared__ float lsum[2][TILE];
    __shared__ int st[TILE];

    const int tid  = threadIdx.x;
    const int lane = tid & 63;
    const int wid  = tid >> 6;
    const int wrow = wid >> 1;   // 0..1 : which 64-row stripe
    const int wcol = wid & 1;    // 0..1 : which 64-col stripe
    const int m0 = blockIdx.x * TILE;
    const int v0 = blockIdx.y * TILE;
    const int vt = blockIdx.y;

    if (tid < TILE) st[tid] = target[m0 + tid];

    f32x4 acc[4][4] = {};

    for (int k0 = 0; k0 < H; k0 += BK) {
        stage_tile(inp, H, m0, k0, As, tid);
        stage_tile(wgt, H, v0, k0, Bs, tid);
        __syncthreads();
        #pragma unroll
        for (int ks = 0; ks < 2; ++ks) {
            const int kk = ks * 32 + ((lane >> 4) << 3);
            bf16x8 a[4], b[4];
            #pragma unroll
            for (int m = 0; m < 4; ++m)
                a[m] = *reinterpret_cast<const bf16x8*>(&As[wrow * 64 + m * 16 + (lane & 15)][kk]);
            #pragma unroll
            for (int n = 0; n < 4; ++n)
                b[n] = *reinterpret_cast<const bf16x8*>(&Bs[wcol * 64 + n * 16 + (lane & 15)][kk]);
            #pragma unroll
            for (int m = 0; m < 4; ++m)
                #pragma unroll
                for (int n = 0; n < 4; ++n)
                    acc[m][n] = __builtin_amdgcn_mfma_f32_16x16x32_bf16(a[m], b[n], acc[m][n], 0, 0, 0);
        }
        __syncthreads();
    }

    // Epilogue: per-row max & sumexp over this block's 128 columns.
    // C/D layout (verified m89/m91): col = lane&15, row = (lane>>4)*4 + reg.
    const int g = lane >> 4, c0 = lane & 15;
    #pragma unroll
    for (int m = 0; m < 4; ++m) {
        #pragma unroll
        for (int j = 0; j < 4; ++j) {
            float vmax = fmaxf(fmaxf(acc[m][0][j], acc[m][1][j]),
                               fmaxf(acc[m][2][j], acc[m][3][j]));
            #pragma unroll
            for (int d = 1; d < 16; d <<= 1)
                vmax = fmaxf(vmax, __shfl_xor(vmax, d));
            float s = 0.f;
            #pragma unroll
            for (int n = 0; n < 4; ++n)
                s += expf(acc[m][n][j] - vmax);
            #pragma unroll
            for (int d = 1; d < 16; d <<= 1)
                s += __shfl_xor(s, d);
            const int row = wrow * 64 + m * 16 + g * 4 + j;
            const int t = st[row];
            #pragma unroll
            for (int n = 0; n < 4; ++n) {
                if (v0 + wcol * 64 + n * 16 + c0 == t)
                    tgt[m0 + row] = acc[m][n][j];
            }
            if (c0 == 0) { lmax[wcol][row] = vmax; lsum[wcol][row] = s; }
        }
    }
    __syncthreads();
    if (tid < TILE) {
        const float ma = lmax[0][tid], mb = lmax[1][tid];
        const float M = fmaxf(ma, mb);
        const float S = lsum[0][tid] * expf(ma - M) + lsum[1][tid] * expf(mb - M);
        const size_t idx = (size_t)(m0 + tid) * Vt + vt;
        pm[idx] = M;
        ps[idx] = S;
    }
}

// Phase 2: per-row merge of Vt partials -> per-row NLL. grid = BT, block = 64.
__global__ void ce_reduce_rows(
    const float* __restrict__ pm, const float* __restrict__ ps,
    const float* __restrict__ tgt, const int* __restrict__ target,
    float* __restrict__ rownll, float* __restrict__ rowvalid, int Vt, int V)
{
    const int row = blockIdx.x;
    const int lane = threadIdx.x;
    float m = -1e30f, s = 0.f;
    for (int vt = lane; vt < Vt; vt += 64) {
        const size_t idx = (size_t)row * Vt + vt;
        const float pmv = pm[idx], psv = ps[idx];
        const float M = fmaxf(m, pmv);
        s = s * expf(m - M) + psv * expf(pmv - M);
        m = M;
    }
    #pragma unroll
    for (int d = 1; d < 64; d <<= 1) {
        const float om = __shfl_xor(m, d), os = __shfl_xor(s, d);
        const float M = fmaxf(m, om);
        s = s * expf(m - M) + os * expf(om - M);
        m = M;
    }
    if (lane == 0) {
        const int t = target[row];
        const bool valid = (t >= 0 && t < V);
        rownll[row]   = valid ? (m + logf(s) - tgt[row]) : 0.f;
        rowvalid[row] = valid ? 1.f : 0.f;
    }
}

// Phase 3: deterministic tree-reduce over rows -> scalar mean.
__global__ void ce_final(
    const float* __restrict__ rownll, const float* __restrict__ rowvalid,
    float* __restrict__ out, int BT)
{
    __shared__ float ssum[256];
    __shared__ float scnt[256];
    const int tid = threadIdx.x;
    float a = 0.f, c = 0.f;
    for (int i = tid; i < BT; i += 256) { a += rownll[i]; c += rowvalid[i]; }
    ssum[tid] = a; scnt[tid] = c;
    __syncthreads();
    for (int d = 128; d; d >>= 1) {
        if (tid < d) { ssum[tid] += ssum[tid + d]; scnt[tid] += scnt[tid + d]; }
        __syncthreads();
    }
    if (tid == 0) out[0] = ssum[0] / fmaxf(scnt[0], 1.f);
}

extern "C" void kernel_launch(void* const* d_in, const int* in_sizes, int n_in,
                              void* d_out, int out_size, void* d_ws, size_t ws_size,
                              hipStream_t stream) {
    (void)n_in; (void)out_size; (void)ws_size;
    const float* inp    = (const float*)d_in[0];
    const float* wgt    = (const float*)d_in[1];
    const int*   target = (const int*)d_in[2];
    float* out = (float*)d_out;

    const int BT = in_sizes[2];
    const int H  = in_sizes[0] / BT;
    const int V  = (int)((long long)in_sizes[1] / H);
    const int Mt = BT / TILE;   // 32
    const int Vt = V / TILE;    // 250

    char* ws = (char*)d_ws;
    float* pm       = (float*)ws;                         size_t o = (size_t)BT * Vt * 4;
    float* ps       = (float*)(ws + o);                   o += (size_t)BT * Vt * 4;
    float* tgt      = (float*)(ws + o);                   o += (size_t)BT * 4;
    float* rownll   = (float*)(ws + o);                   o += (size_t)BT * 4;
    float* rowvalid = (float*)(ws + o);

    // grid.x = M-tiles (fast-varying) so consecutive blocks share the same
    // 2 MB weight panel -> weight streams HBM once, input stays LLC-resident.
    dim3 grid(Mt, Vt);
    ce_gemm_partial<<<grid, 256, 0, stream>>>(inp, wgt, target, pm, ps, tgt, H, Vt);
    ce_reduce_rows<<<BT, 64, 0, stream>>>(pm, ps, tgt, target, rownll, rowvalid, Vt, V);
    ce_final<<<1, 256, 0, stream>>>(rownll, rowvalid, out, BT);
}

// Round 2
// 1499.903 us; speedup vs baseline: 2.5083x; 2.5083x over previous
//
#include <hip/hip_runtime.h>
#include <hip/hip_bf16.h>

#define TILE 128
#define BK 64

typedef __attribute__((ext_vector_type(8))) short bf16x8;
typedef __attribute__((ext_vector_type(4))) float f32x4;

static __device__ __forceinline__ short f2bf(float f) {
    __hip_bfloat16 h = __float2bfloat16(f);
    return *reinterpret_cast<short*>(&h);
}

// ---------------- fp32 -> bf16 conversion (grid-stride, 8 elem/thread) -----
__global__ void cvt_f32_bf16(const float* __restrict__ src,
                             short* __restrict__ dst, long long n) {
    long long i = ((long long)blockIdx.x * blockDim.x + threadIdx.x) * 8;
    const long long stride = (long long)gridDim.x * blockDim.x * 8;
    for (; i < n; i += stride) {
        f32x4 x = *reinterpret_cast<const f32x4*>(src + i);
        f32x4 y = *reinterpret_cast<const f32x4*>(src + i + 4);
        bf16x8 v;
        v[0] = f2bf(x[0]); v[1] = f2bf(x[1]); v[2] = f2bf(x[2]); v[3] = f2bf(x[3]);
        v[4] = f2bf(y[0]); v[5] = f2bf(y[1]); v[6] = f2bf(y[2]); v[7] = f2bf(y[3]);
        *reinterpret_cast<bf16x8*>(dst + i) = v;
    }
}

// ---------------- fast path: bf16 GEMM + fused softmax partials ------------
static __device__ __forceinline__ void gload_lds16(const short* g, short* l) {
    __builtin_amdgcn_global_load_lds(
        (const __attribute__((address_space(1))) void*)g,
        (__attribute__((address_space(3))) void*)l, 16, 0, 0);
}

// grid = 1D Mt*Vt (XCD-swizzled), block = 256 (4 waves, 2x2 of 64x64).
__global__ __launch_bounds__(256, 2) void ce_gemm_bf16(
    const short* __restrict__ inp, const short* __restrict__ wgt,
    const int* __restrict__ target,
    float* __restrict__ pm, float* __restrict__ ps, float* __restrict__ tgt,
    int H, int Mt, int Vt)
{
    __shared__ __align__(16) short As[TILE * BK];
    __shared__ __align__(16) short Bs[TILE * BK];
    __shared__ float lmax[2][TILE];
    __shared__ float lsum[2][TILE];
    __shared__ int st[TILE];

    // bijective XCD swizzle (m204): all Mt blocks of one V-panel -> same XCD
    const int nwg = Mt * Vt;
    const int orig = blockIdx.x;
    const int q = nwg >> 3, r = nwg & 7;
    const int xcd = orig & 7, idx = orig >> 3;
    const int w = (xcd < r ? xcd * (q + 1) : r * (q + 1) + (xcd - r) * q) + idx;
    const int vt = w / Mt;
    const int mt = w - vt * Mt;

    const int tid  = threadIdx.x;
    const int lane = tid & 63;
    const int wv   = tid >> 6;
    const int wrow = wv >> 1;
    const int wcol = wv & 1;
    const int m0 = mt * TILE;
    const int v0 = vt * TILE;

    if (tid < TILE) st[tid] = target[m0 + tid];

    // staging addresses: chunk c = wv*4+i covers rows c*8..c*8+7, lane -> (row,col16B)
    const int srow = (lane >> 3);          // 0..7 within chunk
    const int scol = (lane & 7) * 8;       // bf16 elem offset of this lane's 16B
    const short* aG[4]; const short* bG[4]; short* aL[4]; short* bL[4];
    #pragma unroll
    for (int i = 0; i < 4; ++i) {
        const int c = wv * 4 + i;
        const int row = c * 8 + srow;
        aG[i] = inp + (size_t)(m0 + row) * H + scol;
        bG[i] = wgt + (size_t)(v0 + row) * H + scol;
        aL[i] = As + c * 8 * BK;   // wave-uniform LDS base; HW adds lane*16B
        bL[i] = Bs + c * 8 * BK;
    }

    f32x4 acc[4][4] = {};

    for (int k0 = 0; k0 < H; k0 += BK) {
        #pragma unroll
        for (int i = 0; i < 4; ++i) {
            gload_lds16(aG[i], aL[i]);
            gload_lds16(bG[i], bL[i]);
            aG[i] += BK; bG[i] += BK;
        }
        asm volatile("s_waitcnt vmcnt(0)");
        __syncthreads();
        #pragma unroll
        for (int ks = 0; ks < 2; ++ks) {
            const int kk = ks * 32 + ((lane >> 4) << 3);
            bf16x8 a[4], b[4];
            #pragma unroll
            for (int m = 0; m < 4; ++m)
                a[m] = *reinterpret_cast<const bf16x8*>(&As[(wrow * 64 + m * 16 + (lane & 15)) * BK + kk]);
            #pragma unroll
            for (int n = 0; n < 4; ++n)
                b[n] = *reinterpret_cast<const bf16x8*>(&Bs[(wcol * 64 + n * 16 + (lane & 15)) * BK + kk]);
            #pragma unroll
            for (int m = 0; m < 4; ++m)
                #pragma unroll
                for (int n = 0; n < 4; ++n)
                    acc[m][n] = __builtin_amdgcn_mfma_f32_16x16x32_bf16(a[m], b[n], acc[m][n], 0, 0, 0);
        }
        __syncthreads();
    }

    // per-row max & sumexp over this block's 128 cols.
    // C/D layout: col = lane&15, row = (lane>>4)*4 + reg.
    const int g = lane >> 4, c0 = lane & 15;
    #pragma unroll
    for (int m = 0; m < 4; ++m) {
        #pragma unroll
        for (int j = 0; j < 4; ++j) {
            float vmax = fmaxf(fmaxf(acc[m][0][j], acc[m][1][j]),
                               fmaxf(acc[m][2][j], acc[m][3][j]));
            #pragma unroll
            for (int d = 1; d < 16; d <<= 1)
                vmax = fmaxf(vmax, __shfl_xor(vmax, d));
            float s = 0.f;
            #pragma unroll
            for (int n = 0; n < 4; ++n)
                s += expf(acc[m][n][j] - vmax);
            #pragma unroll
            for (int d = 1; d < 16; d <<= 1)
                s += __shfl_xor(s, d);
            const int row = wrow * 64 + m * 16 + g * 4 + j;
            const int t = st[row];
            #pragma unroll
            for (int n = 0; n < 4; ++n) {
                if (v0 + wcol * 64 + n * 16 + c0 == t)
                    tgt[m0 + row] = acc[m][n][j];
            }
            if (c0 == 0) { lmax[wcol][row] = vmax; lsum[wcol][row] = s; }
        }
    }
    __syncthreads();
    if (tid < TILE) {
        const float ma = lmax[0][tid], mb = lmax[1][tid];
        const float M = fmaxf(ma, mb);
        const float S = lsum[0][tid] * expf(ma - M) + lsum[1][tid] * expf(mb - M);
        const size_t idx2 = (size_t)(m0 + tid) * Vt + vt;
        pm[idx2] = M;
        ps[idx2] = S;
    }
}

// ---------------- fallback path (round-1): fp32 reg-staged -----------------
static __device__ __forceinline__ void stage_tile(
    const float* __restrict__ src, long long ld, int row0, int k0,
    short (*__restrict__ dst)[BK], int tid)
{
    const int r = tid >> 1;
    const int h = (tid & 1) * 32;
    const float* p = src + (long long)(row0 + r) * ld + k0 + h;
    #pragma unroll
    for (int j = 0; j < 4; ++j) {
        f32x4 x = *reinterpret_cast<const f32x4*>(p + j * 8);
        f32x4 y = *reinterpret_cast<const f32x4*>(p + j * 8 + 4);
        bf16x8 v;
        v[0] = f2bf(x[0]); v[1] = f2bf(x[1]); v[2] = f2bf(x[2]); v[3] = f2bf(x[3]);
        v[4] = f2bf(y[0]); v[5] = f2bf(y[1]); v[6] = f2bf(y[2]); v[7] = f2bf(y[3]);
        *reinterpret_cast<bf16x8*>(&dst[r][h + j * 8]) = v;
    }
}

__global__ __launch_bounds__(256, 2) void ce_gemm_partial(
    const float* __restrict__ inp, const float* __restrict__ wgt,
    const int* __restrict__ target,
    float* __restrict__ pm, float* __restrict__ ps, float* __restrict__ tgt,
    int H, int Vt)
{
    __shared__ __align__(16) short As[TILE][BK];
    __shared__ __align__(16) short Bs[TILE][BK];
    __shared__ float lmax[2][TILE];
    __shared__ float lsum[2][TILE];
    __shared__ int st[TILE];

    const int tid  = threadIdx.x;
    const int lane = tid & 63;
    const int wid  = tid >> 6;
    const int wrow = wid >> 1;
    const int wcol = wid & 1;
    const int m0 = blockIdx.x * TILE;
    const int v0 = blockIdx.y * TILE;
    const int vt = blockIdx.y;

    if (tid < TILE) st[tid] = target[m0 + tid];

    f32x4 acc[4][4] = {};

    for (int k0 = 0; k0 < H; k0 += BK) {
        stage_tile(inp, H, m0, k0, As, tid);
        stage_tile(wgt, H, v0, k0, Bs, tid);
        __syncthreads();
        #pragma unroll
        for (int ks = 0; ks < 2; ++ks) {
            const int kk = ks * 32 + ((lane >> 4) << 3);
            bf16x8 a[4], b[4];
            #pragma unroll
            for (int m = 0; m < 4; ++m)
                a[m] = *reinterpret_cast<const bf16x8*>(&As[wrow * 64 + m * 16 + (lane & 15)][kk]);
            #pragma unroll
            for (int n = 0; n < 4; ++n)
                b[n] = *reinterpret_cast<const bf16x8*>(&Bs[wcol * 64 + n * 16 + (lane & 15)][kk]);
            #pragma unroll
            for (int m = 0; m < 4; ++m)
                #pragma unroll
                for (int n = 0; n < 4; ++n)
                    acc[m][n] = __builtin_amdgcn_mfma_f32_16x16x32_bf16(a[m], b[n], acc[m][n], 0, 0, 0);
        }
        __syncthreads();
    }

    const int g = lane >> 4, c0 = lane & 15;
    #pragma unroll
    for (int m = 0; m < 4; ++m) {
        #pragma unroll
        for (int j = 0; j < 4; ++j) {
            float vmax = fmaxf(fmaxf(acc[m][0][j], acc[m][1][j]),
                               fmaxf(acc[m][2][j], acc[m][3][j]));
            #pragma unroll
            for (int d = 1; d < 16; d <<= 1)
                vmax = fmaxf(vmax, __shfl_xor(vmax, d));
            float s = 0.f;
            #pragma unroll
            for (int n = 0; n < 4; ++n)
                s += expf(acc[m][n][j] - vmax);
            #pragma unroll
            for (int d = 1; d < 16; d <<= 1)
                s += __shfl_xor(s, d);
            const int row = wrow * 64 + m * 16 + g * 4 + j;
            const int t = st[row];
            #pragma unroll
            for (int n = 0; n < 4; ++n) {
                if (v0 + wcol * 64 + n * 16 + c0 == t)
                    tgt[m0 + row] = acc[m][n][j];
            }
            if (c0 == 0) { lmax[wcol][row] = vmax; lsum[wcol][row] = s; }
        }
    }
    __syncthreads();
    if (tid < TILE) {
        const float ma = lmax[0][tid], mb = lmax[1][tid];
        const float M = fmaxf(ma, mb);
        const float S = lsum[0][tid] * expf(ma - M) + lsum[1][tid] * expf(mb - M);
        const size_t idx = (size_t)(m0 + tid) * Vt + vt;
        pm[idx] = M;
        ps[idx] = S;
    }
}

// ---------------- reductions ----------------------------------------------
__global__ void ce_reduce_rows(
    const float* __restrict__ pm, const float* __restrict__ ps,
    const float* __restrict__ tgt, const int* __restrict__ target,
    float* __restrict__ rownll, float* __restrict__ rowvalid, int Vt, int V)
{
    const int row = blockIdx.x;
    const int lane = threadIdx.x;
    float m = -1e30f, s = 0.f;
    for (int vt = lane; vt < Vt; vt += 64) {
        const size_t idx = (size_t)row * Vt + vt;
        const float pmv = pm[idx], psv = ps[idx];
        const float M = fmaxf(m, pmv);
        s = s * expf(m - M) + psv * expf(pmv - M);
        m = M;
    }
    #pragma unroll
    for (int d = 1; d < 64; d <<= 1) {
        const float om = __shfl_xor(m, d), os = __shfl_xor(s, d);
        const float M = fmaxf(m, om);
        s = s * expf(m - M) + os * expf(om - M);
        m = M;
    }
    if (lane == 0) {
        const int t = target[row];
        const bool valid = (t >= 0 && t < V);
        rownll[row]   = valid ? (m + logf(s) - tgt[row]) : 0.f;
        rowvalid[row] = valid ? 1.f : 0.f;
    }
}

__global__ void ce_final(
    const float* __restrict__ rownll, const float* __restrict__ rowvalid,
    float* __restrict__ out, int BT)
{
    __shared__ float ssum[256];
    __shared__ float scnt[256];
    const int tid = threadIdx.x;
    float a = 0.f, c = 0.f;
    for (int i = tid; i < BT; i += 256) { a += rownll[i]; c += rowvalid[i]; }
    ssum[tid] = a; scnt[tid] = c;
    __syncthreads();
    for (int d = 128; d; d >>= 1) {
        if (tid < d) { ssum[tid] += ssum[tid + d]; scnt[tid] += scnt[tid + d]; }
        __syncthreads();
    }
    if (tid == 0) out[0] = ssum[0] / fmaxf(scnt[0], 1.f);
}

extern "C" void kernel_launch(void* const* d_in, const int* in_sizes, int n_in,
                              void* d_out, int out_size, void* d_ws, size_t ws_size,
                              hipStream_t stream) {
    (void)n_in; (void)out_size;
    const float* inp    = (const float*)d_in[0];
    const float* wgt    = (const float*)d_in[1];
    const int*   target = (const int*)d_in[2];
    float* out = (float*)d_out;

    const int BT = in_sizes[2];
    const int H  = in_sizes[0] / BT;
    const int V  = (int)((long long)in_sizes[1] / H);
    const int Mt = BT / TILE;   // 32
    const int Vt = V / TILE;    // 250

    const size_t wbf_bytes = (size_t)V * H * 2;
    const size_t ibf_bytes = (size_t)BT * H * 2;
    const size_t pm_bytes  = (size_t)BT * Vt * 4;
    const size_t small     = (size_t)BT * 4;
    const size_t need_fast = wbf_bytes + ibf_bytes + 2 * pm_bytes + 3 * small;

    char* ws = (char*)d_ws;
    if (ws_size >= need_fast) {
        short* wbf = (short*)ws;                      size_t o = wbf_bytes;
        short* ibf = (short*)(ws + o);                o += ibf_bytes;
        float* pm       = (float*)(ws + o);           o += pm_bytes;
        float* ps       = (float*)(ws + o);           o += pm_bytes;
        float* tgt      = (float*)(ws + o);           o += small;
        float* rownll   = (float*)(ws + o);           o += small;
        float* rowvalid = (float*)(ws + o);

        cvt_f32_bf16<<<2048, 256, 0, stream>>>(wgt, wbf, (long long)V * H);
        cvt_f32_bf16<<<512, 256, 0, stream>>>(inp, ibf, (long long)BT * H);
        ce_gemm_bf16<<<Mt * Vt, 256, 0, stream>>>(ibf, wbf, target, pm, ps, tgt, H, Mt, Vt);
        ce_reduce_rows<<<BT, 64, 0, stream>>>(pm, ps, tgt, target, rownll, rowvalid, Vt, V);
        ce_final<<<1, 256, 0, stream>>>(rownll, rowvalid, out, BT);
    } else {
        float* pm       = (float*)ws;                 size_t o = pm_bytes;
        float* ps       = (float*)(ws + o);           o += pm_bytes;
        float* tgt      = (float*)(ws + o);           o += small;
        float* rownll   = (float*)(ws + o);           o += small;
        float* rowvalid = (float*)(ws + o);

        dim3 grid(Mt, Vt);
        ce_gemm_partial<<<grid, 256, 0, stream>>>(inp, wgt, target, pm, ps, tgt, H, Vt);
        ce_reduce_rows<<<BT, 64, 0, stream>>>(pm, ps, tgt, target, rownll, rowvalid, Vt, V);
        ce_final<<<1, 256, 0, stream>>>(rownll, rowvalid, out, BT);
    }
}

// Round 3
// 1136.348 us; speedup vs baseline: 3.3108x; 1.3199x over previous
//
#include <hip/hip_runtime.h>
#include <hip/hip_bf16.h>

typedef __attribute__((ext_vector_type(8))) short bf16x8;
typedef __attribute__((ext_vector_type(4))) float f32x4;

static __device__ __forceinline__ short f2bf(float f) {
    __hip_bfloat16 h = __float2bfloat16(f);
    return *reinterpret_cast<short*>(&h);
}

// ---------------- fp32 -> bf16 conversion ---------------------------------
__global__ void cvt_f32_bf16(const float* __restrict__ src,
                             short* __restrict__ dst, long long n) {
    long long i = ((long long)blockIdx.x * blockDim.x + threadIdx.x) * 8;
    const long long stride = (long long)gridDim.x * blockDim.x * 8;
    for (; i < n; i += stride) {
        f32x4 x = *reinterpret_cast<const f32x4*>(src + i);
        f32x4 y = *reinterpret_cast<const f32x4*>(src + i + 4);
        bf16x8 v;
        v[0] = f2bf(x[0]); v[1] = f2bf(x[1]); v[2] = f2bf(x[2]); v[3] = f2bf(x[3]);
        v[4] = f2bf(y[0]); v[5] = f2bf(y[1]); v[6] = f2bf(y[2]); v[7] = f2bf(y[3]);
        *reinterpret_cast<bf16x8*>(dst + i) = v;
    }
}

static __device__ __forceinline__ void gload_lds16(const short* g, short* l) {
    __builtin_amdgcn_global_load_lds(
        (const __attribute__((address_space(1))) void*)g,
        (__attribute__((address_space(3))) void*)l, 16, 0, 0);
}

// ============== 256x256 8-phase fused GEMM + CE partials ===================
// 512 threads = 8 waves (2 row-waves x 4 col-waves). BK=64, dbuf LDS 128KiB.
// A-rows per wave: m=0..3 -> rows wr*64+m*16 (half0), m=4..7 -> 128+wr*64+(m-4)*16 (half1).
// Phase q computes m = 2q, 2q+1  (A-half0 in phases 0-1, A-half1 in phases 2-3).
// Staging order (distance 5 half-tiles): tile t phases issue
//   q0: Bh1[t+1]  q1: Ah0[t+1]  q2: Ah1[t+1]  q3: Bh0[t+2]
// vmcnt(6) at q1, vmcnt(4) at q3 (counted, never 0 in main loop).
// LDS swizzle: 16B-chunk index c (0..7 within a 128B row) stored at c^(row&7);
// global source pre-swizzled, reads XOR the same involution.

#define STAGE_A(buf, h, tt) do { \
    gload_lds16(aSrc + (size_t)(h) * H128 + (size_t)(tt) * 64, \
                As_s + ((buf) << 14) + (h) * 8192 + w * 1024); \
    gload_lds16(aSrc + (size_t)(h) * H128 + H8 + (size_t)(tt) * 64, \
                As_s + ((buf) << 14) + (h) * 8192 + w * 1024 + 512); \
} while (0)

#define STAGE_B(buf, h, tt) do { \
    gload_lds16(bSrc + (size_t)(h) * H128 + (size_t)(tt) * 64, \
                Bs_s + ((buf) << 14) + (h) * 8192 + w * 1024); \
    gload_lds16(bSrc + (size_t)(h) * H128 + H8 + (size_t)(tt) * 64, \
                Bs_s + ((buf) << 14) + (h) * 8192 + w * 1024 + 512); \
} while (0)

// A frag (m, ks): logical row (m>>2)*128 + wr*64 + (m&3)*16 + (lane&15)
#define LDA(m, ks) (*reinterpret_cast<const bf16x8*>( \
    Ab + aRow + ((m) & 3) * 1024 + ((m) >> 2) * 8192 + ((ks) ? cK1 : cK0)))
#define LDB(n, ks) (*reinterpret_cast<const bf16x8*>( \
    Bb + bRow + (n) * 1024 + ((ks) ? cK1 : cK0)))

#define MFMA_PAIR(q) do { \
    _Pragma("unroll") \
    for (int n = 0; n < 4; ++n) { \
        acc[2*(q)][n]   = __builtin_amdgcn_mfma_f32_16x16x32_bf16(a0k0, bf[n][0], acc[2*(q)][n],   0, 0, 0); \
        acc[2*(q)][n]   = __builtin_amdgcn_mfma_f32_16x16x32_bf16(a0k1, bf[n][1], acc[2*(q)][n],   0, 0, 0); \
        acc[2*(q)+1][n] = __builtin_amdgcn_mfma_f32_16x16x32_bf16(a1k0, bf[n][0], acc[2*(q)+1][n], 0, 0, 0); \
        acc[2*(q)+1][n] = __builtin_amdgcn_mfma_f32_16x16x32_bf16(a1k1, bf[n][1], acc[2*(q)+1][n], 0, 0, 0); \
    } \
} while (0)

#define PHASE_TAIL() do { \
    __builtin_amdgcn_s_barrier(); \
    asm volatile("s_waitcnt lgkmcnt(0)" ::: "memory"); \
    __builtin_amdgcn_sched_barrier(0); \
    __builtin_amdgcn_s_setprio(1); \
} while (0)

#define PHASE_END() do { \
    __builtin_amdgcn_s_setprio(0); \
    __builtin_amdgcn_sched_barrier(0); \
    __builtin_amdgcn_s_barrier(); \
} while (0)

__global__ __launch_bounds__(512, 2) void ce_gemm_bf16_256(
    const short* __restrict__ inp, const short* __restrict__ wgt,
    const int* __restrict__ target,
    float* __restrict__ pm, float* __restrict__ ps, float* __restrict__ tgt,
    int H, int Mt, int Vt)
{
    __shared__ __align__(16) char smem[131072];
    short* As_s = (short*)smem;              // [2][256][64] bf16 = 64 KiB
    short* Bs_s = (short*)(smem + 65536);    // [2][256][64] bf16 = 64 KiB

    const int NT = H >> 6;   // K-tiles

    // bijective XCD swizzle; mt fastest within an XCD chunk -> weight-panel locality
    const int nwg = Mt * Vt;
    const int orig = blockIdx.x;
    const int q8 = nwg >> 3, r8 = nwg & 7;
    const int xcd = orig & 7, idx = orig >> 3;
    const int wg = (xcd < r8 ? xcd * (q8 + 1) : r8 * (q8 + 1) + (xcd - r8) * q8) + idx;
    const int vt = wg / Mt;
    const int mt = wg - vt * Mt;
    const int m0 = mt * 256;
    const int v0 = vt * 256;

    const int tid  = threadIdx.x;
    const int lane = tid & 63;
    const int w    = tid >> 6;     // wave 0..7
    const int wr   = w >> 2;       // 0..1 row-wave
    const int wc   = w & 3;        // 0..3 col-wave

    const size_t H8   = (size_t)H * 8;
    const size_t H128 = (size_t)H * 128;

    // staging source (global, pre-swizzled chunk) for this thread
    const short* aSrc = inp + (size_t)(m0 + w * 16 + (lane >> 3)) * H
                        + ((lane & 7) ^ (lane >> 3)) * 8;
    const short* bSrc = wgt + (size_t)(v0 + w * 16 + (lane >> 3)) * H
                        + ((lane & 7) ^ (lane >> 3)) * 8;

    // read-side per-lane offsets (shorts)
    const int aRow = (wr * 64 + (lane & 15)) * 64;
    const int bRow = (wc * 64 + (lane & 15)) * 64;
    const int cK0 = (((0 << 2) | (lane >> 4)) ^ (lane & 7)) * 8;  // ks=0 chunk
    const int cK1 = (((1 << 2) | (lane >> 4)) ^ (lane & 7)) * 8;  // ks=1 chunk

    f32x4 acc[8][4] = {};

    // ---- prologue: Bh0[0], Bh1[0], Ah0[0], Ah1[0], Bh0[1];  vmcnt(4) ----
    STAGE_B(0, 0, 0);
    STAGE_B(0, 1, 0);
    STAGE_A(0, 0, 0);
    STAGE_A(0, 1, 0);
    if (NT > 1) STAGE_B(1, 0, 1);
    asm volatile("s_waitcnt vmcnt(4)" ::: "memory");
    __builtin_amdgcn_s_barrier();

    for (int t = 0; t < NT; ++t) {
        const int cur = t & 1, nxt = cur ^ 1;
        const short* Ab = As_s + (cur << 14);
        const short* Bb = Bs_s + (cur << 14);

        bf16x8 bf[4][2];
        // ---- q0: read B (8) + A m0,m1 (4); stage Bh1[t+1] ----
        {
            #pragma unroll
            for (int n = 0; n < 4; ++n) { bf[n][0] = LDB(n, 0); bf[n][1] = LDB(n, 1); }
            bf16x8 a0k0 = LDA(0, 0), a0k1 = LDA(0, 1);
            bf16x8 a1k0 = LDA(1, 0), a1k1 = LDA(1, 1);
            if (t + 1 < NT) STAGE_B(nxt, 1, t + 1);
            PHASE_TAIL();
            MFMA_PAIR(0);
            PHASE_END();
        }
        // ---- q1: A m2,m3; stage Ah0[t+1]; vmcnt(6) ----
        {
            bf16x8 a0k0 = LDA(2, 0), a0k1 = LDA(2, 1);
            bf16x8 a1k0 = LDA(3, 0), a1k1 = LDA(3, 1);
            if (t + 1 < NT) STAGE_A(nxt, 0, t + 1);
            asm volatile("s_waitcnt vmcnt(6)" ::: "memory");
            PHASE_TAIL();
            MFMA_PAIR(1);
            PHASE_END();
        }
        // ---- q2: A m4,m5; stage Ah1[t+1] ----
        {
            bf16x8 a0k0 = LDA(4, 0), a0k1 = LDA(4, 1);
            bf16x8 a1k0 = LDA(5, 0), a1k1 = LDA(5, 1);
            if (t + 1 < NT) STAGE_A(nxt, 1, t + 1);
            PHASE_TAIL();
            MFMA_PAIR(2);
            PHASE_END();
        }
        // ---- q3: A m6,m7; stage Bh0[t+2] (into cur buf); vmcnt(4) ----
        {
            bf16x8 a0k0 = LDA(6, 0), a0k1 = LDA(6, 1);
            bf16x8 a1k0 = LDA(7, 0), a1k1 = LDA(7, 1);
            if (t + 2 < NT) STAGE_B(cur, 0, t + 2);
            asm volatile("s_waitcnt vmcnt(4)" ::: "memory");
            PHASE_TAIL();
            MFMA_PAIR(3);
            PHASE_END();
        }
    }

    // ================= epilogue: fused CE partials =========================
    // reuse LDS: lmax[4][256] @0, lsum[4][256] @4096, st[256] @8192
    float* lmax = (float*)smem;
    float* lsum = (float*)(smem + 4096);
    int*   st   = (int*)(smem + 8192);
    __syncthreads();
    if (tid < 256) st[tid] = target[m0 + tid];
    __syncthreads();

    const int g = lane >> 4, c0 = lane & 15;
    #pragma unroll
    for (int m = 0; m < 8; ++m) {
        const int rowbase = ((m >> 2) * 128) + wr * 64 + (m & 3) * 16;
        #pragma unroll
        for (int j = 0; j < 4; ++j) {
            const int row = rowbase + g * 4 + j;
            float vmax = fmaxf(fmaxf(acc[m][0][j], acc[m][1][j]),
                               fmaxf(acc[m][2][j], acc[m][3][j]));
            #pragma unroll
            for (int d = 1; d < 16; d <<= 1)
                vmax = fmaxf(vmax, __shfl_xor(vmax, d));
            float s = 0.f;
            #pragma unroll
            for (int n = 0; n < 4; ++n)
                s += expf(acc[m][n][j] - vmax);
            #pragma unroll
            for (int d = 1; d < 16; d <<= 1)
                s += __shfl_xor(s, d);
            const int tg = st[row];
            #pragma unroll
            for (int n = 0; n < 4; ++n) {
                if (v0 + wc * 64 + n * 16 + c0 == tg)
                    tgt[m0 + row] = acc[m][n][j];
            }
            if (c0 == 0) { lmax[wc * 256 + row] = vmax; lsum[wc * 256 + row] = s; }
        }
    }
    __syncthreads();
    if (tid < 256) {
        float M = lmax[tid];
        M = fmaxf(M, lmax[256 + tid]);
        M = fmaxf(M, lmax[512 + tid]);
        M = fmaxf(M, lmax[768 + tid]);
        float S = lsum[tid]       * expf(lmax[tid]       - M)
                + lsum[256 + tid] * expf(lmax[256 + tid] - M)
                + lsum[512 + tid] * expf(lmax[512 + tid] - M)
                + lsum[768 + tid] * expf(lmax[768 + tid] - M);
        const size_t o = (size_t)(m0 + tid) * Vt + vt;
        pm[o] = M;
        ps[o] = S;
    }
}

// ---------------- fallback path (round-1): fp32 reg-staged 128^2 ----------
#define TILE 128
#define BK 64
static __device__ __forceinline__ void stage_tile(
    const float* __restrict__ src, long long ld, int row0, int k0,
    short (*__restrict__ dst)[BK], int tid)
{
    const int r = tid >> 1;
    const int h = (tid & 1) * 32;
    const float* p = src + (long long)(row0 + r) * ld + k0 + h;
    #pragma unroll
    for (int j = 0; j < 4; ++j) {
        f32x4 x = *reinterpret_cast<const f32x4*>(p + j * 8);
        f32x4 y = *reinterpret_cast<const f32x4*>(p + j * 8 + 4);
        bf16x8 v;
        v[0] = f2bf(x[0]); v[1] = f2bf(x[1]); v[2] = f2bf(x[2]); v[3] = f2bf(x[3]);
        v[4] = f2bf(y[0]); v[5] = f2bf(y[1]); v[6] = f2bf(y[2]); v[7] = f2bf(y[3]);
        *reinterpret_cast<bf16x8*>(&dst[r][h + j * 8]) = v;
    }
}

__global__ __launch_bounds__(256, 2) void ce_gemm_partial(
    const float* __restrict__ inp, const float* __restrict__ wgt,
    const int* __restrict__ target,
    float* __restrict__ pm, float* __restrict__ ps, float* __restrict__ tgt,
    int H, int Vt)
{
    __shared__ __align__(16) short As[TILE][BK];
    __shared__ __align__(16) short Bs[TILE][BK];
    __shared__ float lmax[2][TILE];
    __shared__ float lsum[2][TILE];
    __shared__ int st[TILE];

    const int tid  = threadIdx.x;
    const int lane = tid & 63;
    const int wid  = tid >> 6;
    const int wrow = wid >> 1;
    const int wcol = wid & 1;
    const int m0 = blockIdx.x * TILE;
    const int v0 = blockIdx.y * TILE;
    const int vt = blockIdx.y;

    if (tid < TILE) st[tid] = target[m0 + tid];

    f32x4 acc[4][4] = {};

    for (int k0 = 0; k0 < H; k0 += BK) {
        stage_tile(inp, H, m0, k0, As, tid);
        stage_tile(wgt, H, v0, k0, Bs, tid);
        __syncthreads();
        #pragma unroll
        for (int ks = 0; ks < 2; ++ks) {
            const int kk = ks * 32 + ((lane >> 4) << 3);
            bf16x8 a[4], b[4];
            #pragma unroll
            for (int m = 0; m < 4; ++m)
                a[m] = *reinterpret_cast<const bf16x8*>(&As[wrow * 64 + m * 16 + (lane & 15)][kk]);
            #pragma unroll
            for (int n = 0; n < 4; ++n)
                b[n] = *reinterpret_cast<const bf16x8*>(&Bs[wcol * 64 + n * 16 + (lane & 15)][kk]);
            #pragma unroll
            for (int m = 0; m < 4; ++m)
                #pragma unroll
                for (int n = 0; n < 4; ++n)
                    acc[m][n] = __builtin_amdgcn_mfma_f32_16x16x32_bf16(a[m], b[n], acc[m][n], 0, 0, 0);
        }
        __syncthreads();
    }

    const int g = lane >> 4, c0 = lane & 15;
    #pragma unroll
    for (int m = 0; m < 4; ++m) {
        #pragma unroll
        for (int j = 0; j < 4; ++j) {
            float vmax = fmaxf(fmaxf(acc[m][0][j], acc[m][1][j]),
                               fmaxf(acc[m][2][j], acc[m][3][j]));
            #pragma unroll
            for (int d = 1; d < 16; d <<= 1)
                vmax = fmaxf(vmax, __shfl_xor(vmax, d));
            float s = 0.f;
            #pragma unroll
            for (int n = 0; n < 4; ++n)
                s += expf(acc[m][n][j] - vmax);
            #pragma unroll
            for (int d = 1; d < 16; d <<= 1)
                s += __shfl_xor(s, d);
            const int row = wrow * 64 + m * 16 + g * 4 + j;
            const int t = st[row];
            #pragma unroll
            for (int n = 0; n < 4; ++n) {
                if (v0 + wcol * 64 + n * 16 + c0 == t)
                    tgt[m0 + row] = acc[m][n][j];
            }
            if (c0 == 0) { lmax[wcol][row] = vmax; lsum[wcol][row] = s; }
        }
    }
    __syncthreads();
    if (tid < TILE) {
        const float ma = lmax[0][tid], mb = lmax[1][tid];
        const float M = fmaxf(ma, mb);
        const float S = lsum[0][tid] * expf(ma - M) + lsum[1][tid] * expf(mb - M);
        const size_t idx = (size_t)(m0 + tid) * Vt + vt;
        pm[idx] = M;
        ps[idx] = S;
    }
}

// ---------------- reductions ----------------------------------------------
__global__ void ce_reduce_rows(
    const float* __restrict__ pm, const float* __restrict__ ps,
    const float* __restrict__ tgt, const int* __restrict__ target,
    float* __restrict__ rownll, float* __restrict__ rowvalid, int Vt, int V)
{
    const int row = blockIdx.x;
    const int lane = threadIdx.x;
    float m = -1e30f, s = 0.f;
    for (int vt = lane; vt < Vt; vt += 64) {
        const size_t idx = (size_t)row * Vt + vt;
        const float pmv = pm[idx], psv = ps[idx];
        const float M = fmaxf(m, pmv);
        s = s * expf(m - M) + psv * expf(pmv - M);
        m = M;
    }
    #pragma unroll
    for (int d = 1; d < 64; d <<= 1) {
        const float om = __shfl_xor(m, d), os = __shfl_xor(s, d);
        const float M = fmaxf(m, om);
        s = s * expf(m - M) + os * expf(om - M);
        m = M;
    }
    if (lane == 0) {
        const int t = target[row];
        const bool valid = (t >= 0 && t < V);
        rownll[row]   = valid ? (m + logf(s) - tgt[row]) : 0.f;
        rowvalid[row] = valid ? 1.f : 0.f;
    }
}

__global__ void ce_final(
    const float* __restrict__ rownll, const float* __restrict__ rowvalid,
    float* __restrict__ out, int BT)
{
    __shared__ float ssum[256];
    __shared__ float scnt[256];
    const int tid = threadIdx.x;
    float a = 0.f, c = 0.f;
    for (int i = tid; i < BT; i += 256) { a += rownll[i]; c += rowvalid[i]; }
    ssum[tid] = a; scnt[tid] = c;
    __syncthreads();
    for (int d = 128; d; d >>= 1) {
        if (tid < d) { ssum[tid] += ssum[tid + d]; scnt[tid] += scnt[tid + d]; }
        __syncthreads();
    }
    if (tid == 0) out[0] = ssum[0] / fmaxf(scnt[0], 1.f);
}

extern "C" void kernel_launch(void* const* d_in, const int* in_sizes, int n_in,
                              void* d_out, int out_size, void* d_ws, size_t ws_size,
                              hipStream_t stream) {
    (void)n_in; (void)out_size;
    const float* inp    = (const float*)d_in[0];
    const float* wgt    = (const float*)d_in[1];
    const int*   target = (const int*)d_in[2];
    float* out = (float*)d_out;

    const int BT = in_sizes[2];
    const int H  = in_sizes[0] / BT;
    const int V  = (int)((long long)in_sizes[1] / H);

    const size_t wbf_bytes = (size_t)V * H * 2;
    const size_t ibf_bytes = (size_t)BT * H * 2;

    const bool ok256 = (BT % 256 == 0) && (V % 256 == 0) && (H % 64 == 0) && (H >= 192);

    char* ws = (char*)d_ws;
    if (ok256) {
        const int Mt = BT / 256;   // 16
        const int Vt = V / 256;    // 125
        const size_t pm_bytes = (size_t)BT * Vt * 4;
        const size_t small    = (size_t)BT * 4;
        const size_t need = wbf_bytes + ibf_bytes + 2 * pm_bytes + 3 * small;
        if (ws_size >= need) {
            short* wbf = (short*)ws;                      size_t o = wbf_bytes;
            short* ibf = (short*)(ws + o);                o += ibf_bytes;
            float* pm       = (float*)(ws + o);           o += pm_bytes;
            float* ps       = (float*)(ws + o);           o += pm_bytes;
            float* tgt      = (float*)(ws + o);           o += small;
            float* rownll   = (float*)(ws + o);           o += small;
            float* rowvalid = (float*)(ws + o);

            cvt_f32_bf16<<<2048, 256, 0, stream>>>(wgt, wbf, (long long)V * H);
            cvt_f32_bf16<<<512, 256, 0, stream>>>(inp, ibf, (long long)BT * H);
            ce_gemm_bf16_256<<<Mt * Vt, 512, 0, stream>>>(ibf, wbf, target, pm, ps, tgt, H, Mt, Vt);
            ce_reduce_rows<<<BT, 64, 0, stream>>>(pm, ps, tgt, target, rownll, rowvalid, Vt, V);
            ce_final<<<1, 256, 0, stream>>>(rownll, rowvalid, out, BT);
            return;
        }
    }
    // fallback: fp32 reg-staged 128^2
    {
        const int Mt = BT / TILE;
        const int Vt = V / TILE;
        const size_t pm_bytes = (size_t)BT * Vt * 4;
        const size_t small    = (size_t)BT * 4;
        float* pm       = (float*)ws;                 size_t o = pm_bytes;
        float* ps       = (float*)(ws + o);           o += pm_bytes;
        float* tgt      = (float*)(ws + o);           o += small;
        float* rownll   = (float*)(ws + o);           o += small;
        float* rowvalid = (float*)(ws + o);

        dim3 grid(Mt, Vt);
        ce_gemm_partial<<<grid, 256, 0, stream>>>(inp, wgt, target, pm, ps, tgt, H, Vt);
        ce_reduce_rows<<<BT, 64, 0, stream>>>(pm, ps, tgt, target, rownll, rowvalid, Vt, V);
        ce_final<<<1, 256, 0, stream>>>(rownll, rowvalid, out, BT);
    }
}

// Round 4
// 1087.080 us; speedup vs baseline: 3.4608x; 1.0453x over previous
//
#include <hip/hip_runtime.h>
#include <hip/hip_bf16.h>

typedef __attribute__((ext_vector_type(8))) short bf16x8;
typedef __attribute__((ext_vector_type(4))) float f32x4;

static __device__ __forceinline__ short f2bf(float f) {
    __hip_bfloat16 h = __float2bfloat16(f);
    return *reinterpret_cast<short*>(&h);
}

// ---------------- fp32 -> bf16 conversion ---------------------------------
__global__ void cvt_f32_bf16(const float* __restrict__ src,
                             short* __restrict__ dst, long long n) {
    long long i = ((long long)blockIdx.x * blockDim.x + threadIdx.x) * 8;
    const long long stride = (long long)gridDim.x * blockDim.x * 8;
    for (; i < n; i += stride) {
        f32x4 x = *reinterpret_cast<const f32x4*>(src + i);
        f32x4 y = *reinterpret_cast<const f32x4*>(src + i + 4);
        bf16x8 v;
        v[0] = f2bf(x[0]); v[1] = f2bf(x[1]); v[2] = f2bf(x[2]); v[3] = f2bf(x[3]);
        v[4] = f2bf(y[0]); v[5] = f2bf(y[1]); v[6] = f2bf(y[2]); v[7] = f2bf(y[3]);
        *reinterpret_cast<bf16x8*>(dst + i) = v;
    }
}

static __device__ __forceinline__ void gload_lds16(const short* g, short* l) {
    __builtin_amdgcn_global_load_lds(
        (const __attribute__((address_space(1))) void*)g,
        (__attribute__((address_space(3))) void*)l, 16, 0, 0);
}

// ============== 256x256 fused GEMM + CE partials, 1-barrier/tile ===========
// 512 threads = 8 waves (2 row-waves x 4 col-waves). BK=64, dbuf LDS 128KiB.
// Per tile: 4 MFMA phases (m-pairs), ds_reads for phase q+1 issued BEFORE
// MFMA(q) so the LDS pipe drains under the MFMA pipe. Stagings: one
// half-tile of t+1 per phase, all into nxt. vmcnt(2) at phase1 (drains
// Ah1[t]) and at boundary (drains B[t+1]+Ah0[t+1]); never 0 in steady state.
// LDS swizzle: 16B chunk c of row r stored at c^(r&7); global source
// pre-swizzled, reads XOR the same involution (round-3 verified, 0 conflicts).

#define STAGE_A(buf, h, tt) do { \
    gload_lds16(aSrc + (size_t)(h) * H128 + (size_t)(tt) * 64, \
                As_s + ((buf) << 14) + (h) * 8192 + w * 1024); \
    gload_lds16(aSrc + (size_t)(h) * H128 + H8 + (size_t)(tt) * 64, \
                As_s + ((buf) << 14) + (h) * 8192 + w * 1024 + 512); \
} while (0)

#define STAGE_B(buf, h, tt) do { \
    gload_lds16(bSrc + (size_t)(h) * H128 + (size_t)(tt) * 64, \
                Bs_s + ((buf) << 14) + (h) * 8192 + w * 1024); \
    gload_lds16(bSrc + (size_t)(h) * H128 + H8 + (size_t)(tt) * 64, \
                Bs_s + ((buf) << 14) + (h) * 8192 + w * 1024 + 512); \
} while (0)

#define LDA(m, ks) (*reinterpret_cast<const bf16x8*>( \
    Ab + aRow + ((m) & 3) * 1024 + ((m) >> 2) * 8192 + ((ks) ? cK1 : cK0)))
#define LDB(n, ks) (*reinterpret_cast<const bf16x8*>( \
    Bb + bRow + (n) * 1024 + ((ks) ? cK1 : cK0)))

#define MFMA_Q(q, A00, A01, A10, A11) do { \
    _Pragma("unroll") \
    for (int n = 0; n < 4; ++n) { \
        acc[2*(q)][n]   = __builtin_amdgcn_mfma_f32_16x16x32_bf16(A00, bfr[n][0], acc[2*(q)][n],   0, 0, 0); \
        acc[2*(q)][n]   = __builtin_amdgcn_mfma_f32_16x16x32_bf16(A01, bfr[n][1], acc[2*(q)][n],   0, 0, 0); \
        acc[2*(q)+1][n] = __builtin_amdgcn_mfma_f32_16x16x32_bf16(A10, bfr[n][0], acc[2*(q)+1][n], 0, 0, 0); \
        acc[2*(q)+1][n] = __builtin_amdgcn_mfma_f32_16x16x32_bf16(A11, bfr[n][1], acc[2*(q)+1][n], 0, 0, 0); \
    } \
} while (0)

__global__ __launch_bounds__(512, 2) void ce_gemm_bf16_256(
    const short* __restrict__ inp, const short* __restrict__ wgt,
    const int* __restrict__ target,
    float* __restrict__ pm, float* __restrict__ ps, float* __restrict__ tgt,
    int H, int Mt, int Vt)
{
    __shared__ __align__(16) char smem[131072];
    short* As_s = (short*)smem;              // [2][256][64] bf16 = 64 KiB
    short* Bs_s = (short*)(smem + 65536);    // [2][256][64] bf16 = 64 KiB

    const int NT = H >> 6;   // K-tiles

    // bijective XCD swizzle; mt fastest within an XCD chunk -> weight-panel locality
    const int nwg = Mt * Vt;
    const int orig = blockIdx.x;
    const int q8 = nwg >> 3, r8 = nwg & 7;
    const int xcd = orig & 7, idx = orig >> 3;
    const int wg = (xcd < r8 ? xcd * (q8 + 1) : r8 * (q8 + 1) + (xcd - r8) * q8) + idx;
    const int vt = wg / Mt;
    const int mt = wg - vt * Mt;
    const int m0 = mt * 256;
    const int v0 = vt * 256;

    const int tid  = threadIdx.x;
    const int lane = tid & 63;
    const int w    = tid >> 6;     // wave 0..7
    const int wr   = w >> 2;       // 0..1 row-wave
    const int wc   = w & 3;        // 0..3 col-wave

    const size_t H8   = (size_t)H * 8;
    const size_t H128 = (size_t)H * 128;

    // staging source (global, pre-swizzled chunk) for this thread
    const short* aSrc = inp + (size_t)(m0 + w * 16 + (lane >> 3)) * H
                        + ((lane & 7) ^ (lane >> 3)) * 8;
    const short* bSrc = wgt + (size_t)(v0 + w * 16 + (lane >> 3)) * H
                        + ((lane & 7) ^ (lane >> 3)) * 8;

    // read-side per-lane offsets (shorts)
    const int aRow = (wr * 64 + (lane & 15)) * 64;
    const int bRow = (wc * 64 + (lane & 15)) * 64;
    const int cK0 = (((0 << 2) | (lane >> 4)) ^ (lane & 7)) * 8;
    const int cK1 = (((1 << 2) | (lane >> 4)) ^ (lane & 7)) * 8;

    f32x4 acc[8][4] = {};

    // ---- prologue: stage tile 0 (Bh0,Bh1,Ah0,Ah1); vmcnt(2) leaves Ah1[0]
    STAGE_B(0, 0, 0);
    STAGE_B(0, 1, 0);
    STAGE_A(0, 0, 0);
    STAGE_A(0, 1, 0);
    asm volatile("s_waitcnt vmcnt(2)" ::: "memory");
    __builtin_amdgcn_s_barrier();
    __builtin_amdgcn_sched_barrier(0);

    for (int t = 0; t < NT; ++t) {
        const int cur = t & 1, nxt = cur ^ 1;
        const short* Ab = As_s + (cur << 14);
        const short* Bb = Bs_s + (cur << 14);
        const bool pf = (t + 1 < NT);

        // R0: all B-frags + A m0,m1 (issued right after boundary barrier)
        bf16x8 bfr[4][2];
        #pragma unroll
        for (int n = 0; n < 4; ++n) { bfr[n][0] = LDB(n, 0); bfr[n][1] = LDB(n, 1); }
        bf16x8 p00 = LDA(0, 0), p01 = LDA(0, 1), p10 = LDA(1, 0), p11 = LDA(1, 1);

        // phase 0: issue R1 (m2,m3); stage Bh0[t+1]; MFMA m0,m1
        bf16x8 n00 = LDA(2, 0), n01 = LDA(2, 1), n10 = LDA(3, 0), n11 = LDA(3, 1);
        if (pf) STAGE_B(nxt, 0, t + 1);
        __builtin_amdgcn_sched_barrier(0);
        __builtin_amdgcn_s_setprio(1);
        MFMA_Q(0, p00, p01, p10, p11);
        __builtin_amdgcn_s_setprio(0);
        __builtin_amdgcn_sched_barrier(0);

        // phase 1: drain Ah1[t]; issue R2 (m4,m5); stage Bh1[t+1]; MFMA m2,m3
        if (pf) asm volatile("s_waitcnt vmcnt(2)" ::: "memory");
        else    asm volatile("s_waitcnt vmcnt(0)" ::: "memory");
        p00 = LDA(4, 0); p01 = LDA(4, 1); p10 = LDA(5, 0); p11 = LDA(5, 1);
        if (pf) STAGE_B(nxt, 1, t + 1);
        __builtin_amdgcn_sched_barrier(0);
        __builtin_amdgcn_s_setprio(1);
        MFMA_Q(1, n00, n01, n10, n11);
        __builtin_amdgcn_s_setprio(0);
        __builtin_amdgcn_sched_barrier(0);

        // phase 2: issue R3 (m6,m7); stage Ah0[t+1]; MFMA m4,m5
        n00 = LDA(6, 0); n01 = LDA(6, 1); n10 = LDA(7, 0); n11 = LDA(7, 1);
        if (pf) STAGE_A(nxt, 0, t + 1);
        __builtin_amdgcn_sched_barrier(0);
        __builtin_amdgcn_s_setprio(1);
        MFMA_Q(2, p00, p01, p10, p11);
        __builtin_amdgcn_s_setprio(0);
        __builtin_amdgcn_sched_barrier(0);

        // phase 3: stage Ah1[t+1]; MFMA m6,m7; boundary vmcnt(2)+barrier
        if (pf) STAGE_A(nxt, 1, t + 1);
        __builtin_amdgcn_sched_barrier(0);
        __builtin_amdgcn_s_setprio(1);
        MFMA_Q(3, n00, n01, n10, n11);
        __builtin_amdgcn_s_setprio(0);
        asm volatile("s_waitcnt vmcnt(2)" ::: "memory");
        __builtin_amdgcn_s_barrier();
        __builtin_amdgcn_sched_barrier(0);
    }

    // ================= epilogue: fused CE partials =========================
    float* lmax = (float*)smem;
    float* lsum = (float*)(smem + 4096);
    int*   st   = (int*)(smem + 8192);
    __syncthreads();
    if (tid < 256) st[tid] = target[m0 + tid];
    __syncthreads();

    const int g = lane >> 4, c0 = lane & 15;
    #pragma unroll
    for (int m = 0; m < 8; ++m) {
        const int rowbase = ((m >> 2) * 128) + wr * 64 + (m & 3) * 16;
        #pragma unroll
        for (int j = 0; j < 4; ++j) {
            const int row = rowbase + g * 4 + j;
            float vmax = fmaxf(fmaxf(acc[m][0][j], acc[m][1][j]),
                               fmaxf(acc[m][2][j], acc[m][3][j]));
            #pragma unroll
            for (int d = 1; d < 16; d <<= 1)
                vmax = fmaxf(vmax, __shfl_xor(vmax, d));
            float s = 0.f;
            #pragma unroll
            for (int n = 0; n < 4; ++n)
                s += expf(acc[m][n][j] - vmax);
            #pragma unroll
            for (int d = 1; d < 16; d <<= 1)
                s += __shfl_xor(s, d);
            const int tg = st[row];
            #pragma unroll
            for (int n = 0; n < 4; ++n) {
                if (v0 + wc * 64 + n * 16 + c0 == tg)
                    tgt[m0 + row] = acc[m][n][j];
            }
            if (c0 == 0) { lmax[wc * 256 + row] = vmax; lsum[wc * 256 + row] = s; }
        }
    }
    __syncthreads();
    if (tid < 256) {
        float M = lmax[tid];
        M = fmaxf(M, lmax[256 + tid]);
        M = fmaxf(M, lmax[512 + tid]);
        M = fmaxf(M, lmax[768 + tid]);
        float S = lsum[tid]       * expf(lmax[tid]       - M)
                + lsum[256 + tid] * expf(lmax[256 + tid] - M)
                + lsum[512 + tid] * expf(lmax[512 + tid] - M)
                + lsum[768 + tid] * expf(lmax[768 + tid] - M);
        const size_t o = (size_t)(m0 + tid) * Vt + vt;
        pm[o] = M;
        ps[o] = S;
    }
}

// ---------------- fallback path: fp32 reg-staged 128^2 --------------------
#define TILE 128
#define BK 64
static __device__ __forceinline__ void stage_tile(
    const float* __restrict__ src, long long ld, int row0, int k0,
    short (*__restrict__ dst)[BK], int tid)
{
    const int r = tid >> 1;
    const int h = (tid & 1) * 32;
    const float* p = src + (long long)(row0 + r) * ld + k0 + h;
    #pragma unroll
    for (int j = 0; j < 4; ++j) {
        f32x4 x = *reinterpret_cast<const f32x4*>(p + j * 8);
        f32x4 y = *reinterpret_cast<const f32x4*>(p + j * 8 + 4);
        bf16x8 v;
        v[0] = f2bf(x[0]); v[1] = f2bf(x[1]); v[2] = f2bf(x[2]); v[3] = f2bf(x[3]);
        v[4] = f2bf(y[0]); v[5] = f2bf(y[1]); v[6] = f2bf(y[2]); v[7] = f2bf(y[3]);
        *reinterpret_cast<bf16x8*>(&dst[r][h + j * 8]) = v;
    }
}

__global__ __launch_bounds__(256, 2) void ce_gemm_partial(
    const float* __restrict__ inp, const float* __restrict__ wgt,
    const int* __restrict__ target,
    float* __restrict__ pm, float* __restrict__ ps, float* __restrict__ tgt,
    int H, int Vt)
{
    __shared__ __align__(16) short As[TILE][BK];
    __shared__ __align__(16) short Bs[TILE][BK];
    __shared__ float lmax[2][TILE];
    __shared__ float lsum[2][TILE];
    __shared__ int st[TILE];

    const int tid  = threadIdx.x;
    const int lane = tid & 63;
    const int wid  = tid >> 6;
    const int wrow = wid >> 1;
    const int wcol = wid & 1;
    const int m0 = blockIdx.x * TILE;
    const int v0 = blockIdx.y * TILE;
    const int vt = blockIdx.y;

    if (tid < TILE) st[tid] = target[m0 + tid];

    f32x4 acc[4][4] = {};

    for (int k0 = 0; k0 < H; k0 += BK) {
        stage_tile(inp, H, m0, k0, As, tid);
        stage_tile(wgt, H, v0, k0, Bs, tid);
        __syncthreads();
        #pragma unroll
        for (int ks = 0; ks < 2; ++ks) {
            const int kk = ks * 32 + ((lane >> 4) << 3);
            bf16x8 a[4], b[4];
            #pragma unroll
            for (int m = 0; m < 4; ++m)
                a[m] = *reinterpret_cast<const bf16x8*>(&As[wrow * 64 + m * 16 + (lane & 15)][kk]);
            #pragma unroll
            for (int n = 0; n < 4; ++n)
                b[n] = *reinterpret_cast<const bf16x8*>(&Bs[wcol * 64 + n * 16 + (lane & 15)][kk]);
            #pragma unroll
            for (int m = 0; m < 4; ++m)
                #pragma unroll
                for (int n = 0; n < 4; ++n)
                    acc[m][n] = __builtin_amdgcn_mfma_f32_16x16x32_bf16(a[m], b[n], acc[m][n], 0, 0, 0);
        }
        __syncthreads();
    }

    const int g = lane >> 4, c0 = lane & 15;
    #pragma unroll
    for (int m = 0; m < 4; ++m) {
        #pragma unroll
        for (int j = 0; j < 4; ++j) {
            float vmax = fmaxf(fmaxf(acc[m][0][j], acc[m][1][j]),
                               fmaxf(acc[m][2][j], acc[m][3][j]));
            #pragma unroll
            for (int d = 1; d < 16; d <<= 1)
                vmax = fmaxf(vmax, __shfl_xor(vmax, d));
            float s = 0.f;
            #pragma unroll
            for (int n = 0; n < 4; ++n)
                s += expf(acc[m][n][j] - vmax);
            #pragma unroll
            for (int d = 1; d < 16; d <<= 1)
                s += __shfl_xor(s, d);
            const int row = wrow * 64 + m * 16 + g * 4 + j;
            const int t = st[row];
            #pragma unroll
            for (int n = 0; n < 4; ++n) {
                if (v0 + wcol * 64 + n * 16 + c0 == t)
                    tgt[m0 + row] = acc[m][n][j];
            }
            if (c0 == 0) { lmax[wcol][row] = vmax; lsum[wcol][row] = s; }
        }
    }
    __syncthreads();
    if (tid < TILE) {
        const float ma = lmax[0][tid], mb = lmax[1][tid];
        const float M = fmaxf(ma, mb);
        const float S = lsum[0][tid] * expf(ma - M) + lsum[1][tid] * expf(mb - M);
        const size_t idx = (size_t)(m0 + tid) * Vt + vt;
        pm[idx] = M;
        ps[idx] = S;
    }
}

// ---------------- reductions ----------------------------------------------
__global__ void ce_reduce_rows(
    const float* __restrict__ pm, const float* __restrict__ ps,
    const float* __restrict__ tgt, const int* __restrict__ target,
    float* __restrict__ rownll, float* __restrict__ rowvalid, int Vt, int V)
{
    const int row = blockIdx.x;
    const int lane = threadIdx.x;
    float m = -1e30f, s = 0.f;
    for (int vt = lane; vt < Vt; vt += 64) {
        const size_t idx = (size_t)row * Vt + vt;
        const float pmv = pm[idx], psv = ps[idx];
        const float M = fmaxf(m, pmv);
        s = s * expf(m - M) + psv * expf(pmv - M);
        m = M;
    }
    #pragma unroll
    for (int d = 1; d < 64; d <<= 1) {
        const float om = __shfl_xor(m, d), os = __shfl_xor(s, d);
        const float M = fmaxf(m, om);
        s = s * expf(m - M) + os * expf(om - M);
        m = M;
    }
    if (lane == 0) {
        const int t = target[row];
        const bool valid = (t >= 0 && t < V);
        rownll[row]   = valid ? (m + logf(s) - tgt[row]) : 0.f;
        rowvalid[row] = valid ? 1.f : 0.f;
    }
}

__global__ void ce_final(
    const float* __restrict__ rownll, const float* __restrict__ rowvalid,
    float* __restrict__ out, int BT)
{
    __shared__ float ssum[256];
    __shared__ float scnt[256];
    const int tid = threadIdx.x;
    float a = 0.f, c = 0.f;
    for (int i = tid; i < BT; i += 256) { a += rownll[i]; c += rowvalid[i]; }
    ssum[tid] = a; scnt[tid] = c;
    __syncthreads();
    for (int d = 128; d; d >>= 1) {
        if (tid < d) { ssum[tid] += ssum[tid + d]; scnt[tid] += scnt[tid + d]; }
        __syncthreads();
    }
    if (tid == 0) out[0] = ssum[0] / fmaxf(scnt[0], 1.f);
}

extern "C" void kernel_launch(void* const* d_in, const int* in_sizes, int n_in,
                              void* d_out, int out_size, void* d_ws, size_t ws_size,
                              hipStream_t stream) {
    (void)n_in; (void)out_size;
    const float* inp    = (const float*)d_in[0];
    const float* wgt    = (const float*)d_in[1];
    const int*   target = (const int*)d_in[2];
    float* out = (float*)d_out;

    const int BT = in_sizes[2];
    const int H  = in_sizes[0] / BT;
    const int V  = (int)((long long)in_sizes[1] / H);

    const size_t wbf_bytes = (size_t)V * H * 2;
    const size_t ibf_bytes = (size_t)BT * H * 2;

    const bool ok256 = (BT % 256 == 0) && (V % 256 == 0) && (H % 64 == 0) && (H >= 192);

    char* ws = (char*)d_ws;
    if (ok256) {
        const int Mt = BT / 256;   // 16
        const int Vt = V / 256;    // 125
        const size_t pm_bytes = (size_t)BT * Vt * 4;
        const size_t small    = (size_t)BT * 4;
        const size_t need = wbf_bytes + ibf_bytes + 2 * pm_bytes + 3 * small;
        if (ws_size >= need) {
            short* wbf = (short*)ws;                      size_t o = wbf_bytes;
            short* ibf = (short*)(ws + o);                o += ibf_bytes;
            float* pm       = (float*)(ws + o);           o += pm_bytes;
            float* ps       = (float*)(ws + o);           o += pm_bytes;
            float* tgt      = (float*)(ws + o);           o += small;
            float* rownll   = (float*)(ws + o);           o += small;
            float* rowvalid = (float*)(ws + o);

            cvt_f32_bf16<<<2048, 256, 0, stream>>>(wgt, wbf, (long long)V * H);
            cvt_f32_bf16<<<512, 256, 0, stream>>>(inp, ibf, (long long)BT * H);
            ce_gemm_bf16_256<<<Mt * Vt, 512, 0, stream>>>(ibf, wbf, target, pm, ps, tgt, H, Mt, Vt);
            ce_reduce_rows<<<BT, 64, 0, stream>>>(pm, ps, tgt, target, rownll, rowvalid, Vt, V);
            ce_final<<<1, 256, 0, stream>>>(rownll, rowvalid, out, BT);
            return;
        }
    }
    // fallback: fp32 reg-staged 128^2
    {
        const int Mt = BT / TILE;
        const int Vt = V / TILE;
        const size_t pm_bytes = (size_t)BT * Vt * 4;
        const size_t small    = (size_t)BT * 4;
        float* pm       = (float*)ws;                 size_t o = pm_bytes;
        float* ps       = (float*)(ws + o);           o += pm_bytes;
        float* tgt      = (float*)(ws + o);           o += small;
        float* rownll   = (float*)(ws + o);           o += small;
        float* rowvalid = (float*)(ws + o);

        dim3 grid(Mt, Vt);
        ce_gemm_partial<<<grid, 256, 0, stream>>>(inp, wgt, target, pm, ps, tgt, H, Vt);
        ce_reduce_rows<<<BT, 64, 0, stream>>>(pm, ps, tgt, target, rownll, rowvalid, Vt, V);
        ce_final<<<1, 256, 0, stream>>>(rownll, rowvalid, out, BT);
    }
}